// Round 3
// baseline (353.694 us; speedup 1.0000x reference)
//
#include <hip/hip_runtime.h>
#include <math.h>

// SSIM loss, fused single pass.
// R7 = R6 + packed-FP32 math. MI355X FP32 peak (157 TF) is 2x the scalar
// issue rate and only reachable via v_pk_{fma,mul,add}_f32 (VOP3P), which
// LLVM selects from <2 x float> ops (ext_vector_type). Channels are already
// paired -- (u,v) and (u^2,v^2) -- so h-blur drops 6->3 issue slots/tap,
// v-blur 44->22, tail ~16->~11. Per-component arithmetic identical to R6.
// R6: 4-channel algebraic reduction (u=x+y, v=x-y basis; SSIM needs only
//     mxx+myy): 4mxmy=MU^2-MV^2, 2(mx^2+my^2)=MU^2+MV^2, 4mxy=MUU-MVV,
//     2(mxx+myy)=MUU+MVV. NCHUNKY=3 for occupancy.
// R4 lesson kept: ring buffers as NAMED values (macro-unrolled ring phases)
// so they are SSA by construction -> guaranteed VGPRs.

typedef float v2f __attribute__((ext_vector_type(2)));

#define KS    11
#define IMG_H 256
#define IMG_W 256
#define PADW  268          // tap reads up to col 265, no guard needed
#define OUTD  246
#define NIMG  496
#define OUT_ROWS 82        // 3 y-chunks x 82 = 246
#define NCHUNKY  3
#define NCHUNKS  9         // ceil((82+10)/11)
#define C1F   0.0001f
#define C2F   0.0009f

// 11-tap gaussian (sigma=1.5), normalized; computed in double offline.
__device__ constexpr float GW[KS] = {
    0.00102838f, 0.00759876f, 0.03600077f, 0.10936068f, 0.21300554f,
    0.26601173f,
    0.21300554f, 0.10936068f, 0.03600077f, 0.00759876f, 0.00102838f
};

// horizontal blur of row K of the staged tile, result -> ring slot C
// packed channels: suv = (blur(u), blur(v)), sq = (blur(u^2), blur(v^2))
#define HBLUR_STORE(K, C)                                                  \
  do {                                                                     \
    v2f huv = {0.f, 0.f}, hq = {0.f, 0.f};                                 \
    _Pragma("unroll")                                                      \
    for (int t = 0; t < KS; ++t) {                                         \
      const v2f val = rowbuf[K][tid + t];                                  \
      const v2f wv  = GW[t] * val;        /* v_pk_mul_f32 */               \
      huv += wv;                          /* v_pk_add_f32 */               \
      hq  += wv * val;                    /* v_pk_fma_f32 */               \
    }                                                                      \
    suv##C = huv; sq##C = hq;                                              \
  } while (0)

#define VDOT(M, t0,t1,t2,t3,t4,t5,t6,t7,t8,t9,t10)                         \
  (GW[0]*M##t0 + GW[1]*M##t1 + GW[2]*M##t2 + GW[3]*M##t3 + GW[4]*M##t4     \
 + GW[5]*M##t5 + GW[6]*M##t6 + GW[7]*M##t7 + GW[8]*M##t8 + GW[9]*M##t9     \
 + GW[10]*M##t10)

// one ring phase: h-blur row jj+K into slot K (== t10), then if a full 11-row
// window is resident, v-blur (taps read slots (K+1+t)%11 = t0..t10) + SSIM.
// Reconstruction (A=MU^2, B=MV^2):
//   2 mx my     = (A-B)/2        mx^2+my^2      = (A+B)/2
//   2 m(xy)     = (MUU-MVV)/2    m(xx)+m(yy)    = (MUU+MVV)/2
//   num = (0.5 dAB + C1)(0.5 (dM-dAB) + C2)
//   den = (0.5 sAB + C1)(0.5 (sM-sAB) + C2)
#define STEP(K, t0,t1,t2,t3,t4,t5,t6,t7,t8,t9,t10)                         \
  HBLUR_STORE(K, t10);                                                     \
  {                                                                        \
    const int jrow = jj + K;                                               \
    const int irow = jrow - (KS - 1);                                      \
    if (jrow >= KS - 1 && irow < OUT_ROWS) {   /* wave-uniform */          \
      const v2f MUV = VDOT(suv, t0,t1,t2,t3,t4,t5,t6,t7,t8,t9,t10);       \
      const v2f MQ  = VDOT(sq,  t0,t1,t2,t3,t4,t5,t6,t7,t8,t9,t10);       \
      const v2f AB  = MUV * MUV;           /* (MU^2, MV^2) */              \
      v2f dsAB; dsAB.x = AB.x - AB.y; dsAB.y = AB.x + AB.y;                \
      v2f dsM;  dsM.x  = MQ.x - MQ.y; dsM.y  = MQ.x + MQ.y;                \
      const v2f p1 = 0.5f * dsAB + C1F;          /* (n1, d1) */            \
      const v2f p2 = 0.5f * (dsM - dsAB) + C2F;  /* (n2, d2) */            \
      const v2f nd = p1 * p2;                    /* (num, den) */          \
      ssum += active ? nd.x * __builtin_amdgcn_rcpf(nd.y) : 0.f;           \
    }                                                                      \
  }

__global__ __launch_bounds__(256, 4)
void ssim_fused_kernel(const float* __restrict__ X, const float* __restrict__ Y,
                       double* __restrict__ accum) {
    __shared__ v2f   rowbuf[KS][PADW];
    __shared__ float wsum[4];

    const int img    = blockIdx.x;
    const int out_r0 = blockIdx.y * OUT_ROWS;
    const int tid    = threadIdx.x;
    const bool active = (tid < OUTD);

    const float* Xi = X + (size_t)img * (IMG_H * IMG_W);
    const float* Yi = Y + (size_t)img * (IMG_H * IMG_W);

    // 22 named packed ring registers (slot = local_row % 11), 44 VGPRs
    v2f suv0={0.f,0.f},suv1={0.f,0.f},suv2={0.f,0.f},suv3={0.f,0.f},
        suv4={0.f,0.f},suv5={0.f,0.f},suv6={0.f,0.f},suv7={0.f,0.f},
        suv8={0.f,0.f},suv9={0.f,0.f},suv10={0.f,0.f};
    v2f sq0={0.f,0.f},sq1={0.f,0.f},sq2={0.f,0.f},sq3={0.f,0.f},
        sq4={0.f,0.f},sq5={0.f,0.f},sq6={0.f,0.f},sq7={0.f,0.f},
        sq8={0.f,0.f},sq9={0.f,0.f},sq10={0.f,0.f};

    float ssum = 0.0f;

    for (int c = 0; c < NCHUNKS; ++c) {
        const int jj = c * KS;
        __syncthreads();
        #pragma unroll
        for (int r = 0; r < KS; ++r) {
            int row = out_r0 + jj + r;
            row = min(row, IMG_H - 1);   // clamped rows feed discarded outputs
            const float xv = Xi[(row << 8) + tid];
            const float yv = Yi[(row << 8) + tid];
            v2f uv; uv.x = xv + yv; uv.y = xv - yv;
            rowbuf[r][tid] = uv;
        }
        __syncthreads();

        STEP(0,  1,2,3,4,5,6,7,8,9,10,0)
        STEP(1,  2,3,4,5,6,7,8,9,10,0,1)
        STEP(2,  3,4,5,6,7,8,9,10,0,1,2)
        STEP(3,  4,5,6,7,8,9,10,0,1,2,3)
        STEP(4,  5,6,7,8,9,10,0,1,2,3,4)
        STEP(5,  6,7,8,9,10,0,1,2,3,4,5)
        STEP(6,  7,8,9,10,0,1,2,3,4,5,6)
        STEP(7,  8,9,10,0,1,2,3,4,5,6,7)
        STEP(8,  9,10,0,1,2,3,4,5,6,7,8)
        STEP(9,  10,0,1,2,3,4,5,6,7,8,9)
        STEP(10, 0,1,2,3,4,5,6,7,8,9,10)
    }

    // block reduction
    #pragma unroll
    for (int off = 32; off > 0; off >>= 1)
        ssum += __shfl_down(ssum, off);
    const int lane = tid & 63, wid = tid >> 6;
    if (lane == 0) wsum[wid] = ssum;
    __syncthreads();
    if (tid == 0) {
        const double s = (double)wsum[0] + (double)wsum[1]
                       + (double)wsum[2] + (double)wsum[3];
        atomicAdd(accum, s);
    }
}

__global__ void ssim_finalize_kernel(const double* __restrict__ accum,
                                     float* __restrict__ out) {
    const double cnt = (double)NIMG * OUTD * OUTD;   // 30,015,936
    out[0] = (float)(1.0 - accum[0] / cnt);
}

extern "C" void kernel_launch(void* const* d_in, const int* in_sizes, int n_in,
                              void* d_out, int out_size, void* d_ws, size_t ws_size,
                              hipStream_t stream) {
    (void)in_sizes; (void)n_in; (void)out_size; (void)ws_size;
    const float* X = (const float*)d_in[0];
    const float* Y = (const float*)d_in[1];
    float* out = (float*)d_out;
    double* acc = (double*)d_ws;

    hipMemsetAsync(d_ws, 0, sizeof(double), stream);

    dim3 grid(NIMG, NCHUNKY);
    hipLaunchKernelGGL(ssim_fused_kernel, grid, dim3(256), 0, stream, X, Y, acc);
    hipLaunchKernelGGL(ssim_finalize_kernel, dim3(1), dim3(1), 0, stream, acc, out);
}